// Round 6
// baseline (171.895 us; speedup 1.0000x reference)
//
#include <hip/hip_runtime.h>
#include <hip/hip_fp16.h>

// Trilinear 3D-LUT interpolation (image-adaptive-3DLUT forward).
// lut: [3, 33, 33, 33] fp32, x: [4, 3, 1024, 1024] fp32 in [0,1], out same as x.
//
// R6: global cell-table (R4b) proved divergent GLOBAL gathers are TA-limited
// (61-66 us, all pipes idle). Return to the LDS-gather skeleton (R3, ~38 us)
// and attack its occupancy cap: store the per-channel LUT as PLAIN fp16
// (71.9 KB instead of 143.7 KB fp16-pairs) -> 2 blocks/CU = 8 waves/SIMD
// (was 4). 8x ds_read_u16 per pixel-channel (same LDS bank-touch count as
// 4x b32-pair). VGPR capped <=64 via __launch_bounds__(1024,8) so both
// blocks actually fit. Grid 1536 = 3 channels x 512 chunks, ITERS=2 ->
// every round is exactly 2 blocks/CU. fp16 pre-pack + global_load_lds
// staging + XCD swizzle + NT stores kept from R3.

#define LUT_D    33
#define LUT_DD   (LUT_D * LUT_D)           // 1089
#define LUT_N    (LUT_D * LUT_D * LUT_D)   // 35937
#define CH_H     36000                     // fp16 slots per channel (72000 B, %16==0)
#define STAGE_G4 4500                      // 16B groups per channel (72000/16)
#define HW4      (1024 * 1024 / 4)         // 262144 float4 groups per plane
#define NG       (4 * HW4)                 // 1048576 groups per channel-pass
#define NCHUNKS  512
#define THREADS  1024
#define GPB      (NG / NCHUNKS)            // 2048 groups per block
#define ITERS    (GPB / THREADS)           // 2

typedef float vfloat4 __attribute__((ext_vector_type(4)));

// ---- Pass 1: lut fp32 -> plain fp16 per-channel arrays in ws.
__global__ __launch_bounds__(256)
void lut_pack_kernel(const float* __restrict__ lut, __half* __restrict__ W) {
    const int t = blockIdx.x * 256 + (int)threadIdx.x;
    if (t >= 3 * LUT_N) return;
    const int c = t / LUT_N;
    const int i = t - c * LUT_N;
    W[c * CH_H + i] = __float2half(lut[t]);
    // tail [LUT_N, CH_H) stays poisoned; staged into LDS but never gathered
    // (max gathered index = 35936 < LUT_N).
}

// ---- Pass 2: main interpolation. Block = (channel, pixel chunk).
__global__ __launch_bounds__(THREADS, 8)   // 8 waves/EU -> 2 blocks/CU, VGPR<=64
void lut3d_trilerp_kernel(const __half* __restrict__ W,
                          const float* __restrict__ x,
                          float* __restrict__ out) {
    extern __shared__ __align__(16) __half sl[];   // CH_H fp16 = 72000 B

    const int bx    = blockIdx.x;
    // XCD swizzle: the 3 channel-blocks of one chunk share bx%8 -> same XCD L2.
    const int xcd   = bx & 7;
    const int c     = (bx >> 3) % 3;
    const int chunk = (bx / 24) * 8 + xcd;         // [0, 512)

    // Async stage: 72000 B via global_load_lds dwordx4 (5 sweeps, last partial).
    const char* srcb = (const char*)W + (size_t)c * (CH_H * 2);
    for (int s = 0; s < 5; ++s) {
        const int gid = s * THREADS + (int)threadIdx.x;
        if (gid < STAGE_G4) {
            __builtin_amdgcn_global_load_lds(
                (const __attribute__((address_space(1))) void*)(srcb + gid * 16),
                (__attribute__((address_space(3))) void*)((char*)sl + gid * 16),
                16, 0, 0);
        }
    }
    __syncthreads();   // vmcnt(0) drain before barrier -> staging complete

    const float4* x4 = (const float4*)x;
    float4*       o4 = (float4*)out;

    const int g0 = chunk * GPB + (int)threadIdx.x;

#pragma unroll
    for (int it = 0; it < ITERS; ++it) {
        const int g     = g0 + it * THREADS;
        const int b_img = g >> 18;             // g / HW4
        const int hw4   = g & (HW4 - 1);
        const int ibase = b_img * 3 * HW4 + hw4;

        const float4 r4 = x4[ibase];
        const float4 g4 = x4[ibase + HW4];
        const float4 b4 = x4[ibase + 2 * HW4];

        const float RR[4] = {r4.x, r4.y, r4.z, r4.w};
        const float GG[4] = {g4.x, g4.y, g4.z, g4.w};
        const float BB[4] = {b4.x, b4.y, b4.z, b4.w};

        int   idx[4];
        float dr[4], dg[4], db[4];
#pragma unroll
        for (int k = 0; k < 4; ++k) {
            const float sr = RR[k] * 32.0f;
            const float sg = GG[k] * 32.0f;
            const float sb = BB[k] * 32.0f;
            // idx = clip(floor(s), 0, 31); d = s - idx   (matches reference)
            const float fr = fminf(fmaxf(floorf(sr), 0.0f), 31.0f);
            const float fg = fminf(fmaxf(floorf(sg), 0.0f), 31.0f);
            const float fb = fminf(fmaxf(floorf(sb), 0.0f), 31.0f);
            dr[k] = sr - fr;
            dg[k] = sg - fg;
            db[k] = sb - fb;
            idx[k] = ((int)fb * LUT_D + (int)fg) * LUT_D + (int)fr;
        }

        float oo[4];
        // Process 2 pixels per batch: 16 u16 gathers in flight, VGPR-friendly.
#pragma unroll
        for (int kk = 0; kk < 4; kk += 2) {
            __half h[2][8];
#pragma unroll
            for (int j = 0; j < 2; ++j) {
                const int i0 = idx[kk + j];
                h[j][0] = sl[i0];
                h[j][1] = sl[i0 + 1];
                h[j][2] = sl[i0 + LUT_D];
                h[j][3] = sl[i0 + LUT_D + 1];
                h[j][4] = sl[i0 + LUT_DD];
                h[j][5] = sl[i0 + LUT_DD + 1];
                h[j][6] = sl[i0 + LUT_DD + LUT_D];
                h[j][7] = sl[i0 + LUT_DD + LUT_D + 1];
            }
#pragma unroll
            for (int j = 0; j < 2; ++j) {
                const int k = kk + j;
                const float v000 = __half2float(h[j][0]);
                const float v001 = __half2float(h[j][1]);
                const float v010 = __half2float(h[j][2]);
                const float v011 = __half2float(h[j][3]);
                const float v100 = __half2float(h[j][4]);
                const float v101 = __half2float(h[j][5]);
                const float v110 = __half2float(h[j][6]);
                const float v111 = __half2float(h[j][7]);
                const float l00 = v000 + dr[k] * (v001 - v000);
                const float l01 = v010 + dr[k] * (v011 - v010);
                const float l10 = v100 + dr[k] * (v101 - v100);
                const float l11 = v110 + dr[k] * (v111 - v110);
                const float l0  = l00 + dg[k] * (l01 - l00);
                const float l1  = l10 + dg[k] * (l11 - l10);
                oo[k] = l0 + db[k] * (l1 - l0);
            }
        }

        vfloat4 v = {oo[0], oo[1], oo[2], oo[3]};
        __builtin_nontemporal_store(v, (vfloat4*)&o4[ibase + c * HW4]);
    }
}

extern "C" void kernel_launch(void* const* d_in, const int* in_sizes, int n_in,
                              void* d_out, int out_size, void* d_ws, size_t ws_size,
                              hipStream_t stream) {
    const float* lut = (const float*)d_in[0];  // [3, 33, 33, 33]
    const float* x   = (const float*)d_in[1];  // [4, 3, 1024, 1024]
    float*       out = (float*)d_out;
    __half*      W   = (__half*)d_ws;          // 3 * CH_H fp16 = 216000 B

    const int pack_grid = (3 * LUT_N + 255) / 256;  // 422
    lut_pack_kernel<<<pack_grid, 256, 0, stream>>>(lut, W);

    const int grid = 3 * NCHUNKS;                   // 1536
    const size_t lds_bytes = (size_t)CH_H * 2;      // 72000 B -> 2 blocks/CU
    lut3d_trilerp_kernel<<<grid, THREADS, lds_bytes, stream>>>(W, x, out);
}

// Round 8
// 120.479 us; speedup vs baseline: 1.4268x; 1.4268x over previous
//
#include <hip/hip_runtime.h>
#include <hip/hip_fp16.h>

// Trilinear 3D-LUT interpolation (image-adaptive-3DLUT forward).
// lut: [3, 33, 33, 33] fp32, x: [4, 3, 1024, 1024] fp32 in [0,1], out same as x.
//
// R7b: R7 pipeline with the obase-clobber fixed (store addresses carried in a
// per-iteration array indexed by compile-time t, not the 2-deep rotating buf).
// Structure: R3 skeleton (fp16-pair b32 LDS table, 143.7 KB, 1 block/CU,
// 16 waves) + 3-stage in-wave software pipeline:
//   iter t: load_x(t+2) | idx(t+1) + gather(t+1) | math+store(t)
// Gathers as P[i],P[i+33] pairs -> ds_read2_b32 (2 LDS instrs/pixel-channel).
// fp16-pair pre-pack kernel, global_load_lds staging, XCD swizzle, NT stores.

#define LUT_D     33
#define LUT_DD    (LUT_D * LUT_D)            // 1089
#define LUT_N     (LUT_D * LUT_D * LUT_D)    // 35937
#define CH_STRIDE 35940                      // u32 per channel in ws, 16B-aligned
#define STAGE_G   (CH_STRIDE / 4)            // 8985 dwordx4 groups per channel
#define HW4       (1024 * 1024 / 4)          // 262144 float4 groups per plane
#define NG        (4 * HW4)                  // 1048576 groups per channel-pass
#define NCHUNKS   256
#define THREADS   1024
#define ITERS     (NG / NCHUNKS / THREADS)   // 4

typedef float vfloat4 __attribute__((ext_vector_type(4)));

__device__ __forceinline__ unsigned int pack2(float a, float b) {
    union { __half2 h; unsigned int u; } cv;
    cv.h = __floats2half2_rn(a, b);
    return cv.u;
}
__device__ __forceinline__ float2 up2(unsigned int p) {
    union { unsigned int u; __half2 h; } cv;
    cv.u = p;
    return __half22float2(cv.h);
}

// ---- Pass 1: pack lut fp32 -> fp16 pair array W[c*CH_STRIDE + i] = (v[i], v[i+1])
__global__ __launch_bounds__(256)
void lut_pack_kernel(const float* __restrict__ lut, unsigned int* __restrict__ W) {
    const int t = blockIdx.x * 256 + (int)threadIdx.x;
    if (t >= 3 * LUT_N) return;
    const int c = t / LUT_N;
    const int i = t - c * LUT_N;
    const float a = lut[t];
    const float b = (i + 1 < LUT_N) ? lut[t + 1] : 0.0f;
    W[c * CH_STRIDE + i] = pack2(a, b);
}

// ---- Pass 2: main interpolation, software-pipelined.
__global__ __launch_bounds__(THREADS)
void lut3d_trilerp_kernel(const unsigned int* __restrict__ W,
                          const float* __restrict__ x,
                          float* __restrict__ out) {
    extern __shared__ __align__(16) unsigned int P[];  // 143,760 B

    const int bx    = blockIdx.x;
    // XCD swizzle: the 3 channel-blocks of one chunk share bx%8 -> same XCD L2.
    const int xcd   = bx & 7;
    const int c     = (bx >> 3) % 3;
    const int chunk = (bx / 24) * 8 + xcd;   // [0, 256)

    // Async stage: 143,760 B of packed pairs via global_load_lds dwordx4.
    const unsigned int* src = W + c * CH_STRIDE;
    for (int s = 0; s < 9; ++s) {
        const int gid = s * THREADS + (int)threadIdx.x;
        if (gid < STAGE_G) {
            __builtin_amdgcn_global_load_lds(
                (const __attribute__((address_space(1))) void*)(src + gid * 4),
                (__attribute__((address_space(3))) void*)(P + gid * 4),
                16, 0, 0);
        }
    }

    const float4* x4 = (const float4*)x;
    float4*       o4 = (float4*)out;
    const int g0 = chunk * (NG / NCHUNKS) + (int)threadIdx.x;

    // Pipeline state. x/idx/q rotate on 2 buffers (parity); store addresses
    // are per-iteration (compile-time index -> registers, no clobber).
    float4 Rx[2], Gx[2], Bx[2];
    int    obase_t[ITERS];
    int    idxA[2][4];
    float  drA[2][4], dgA[2][4], dbA[2][4];
    unsigned int q[2][4][4];   // [buf][pixel][pair]: (i, i+33, i+1089, i+1122)

#define LOAD_X(t, buf)                                              \
    {                                                               \
        const int g     = g0 + (t) * THREADS;                       \
        const int b_img = g >> 18;                                  \
        const int hw4   = g & (HW4 - 1);                            \
        const int ibase = b_img * 3 * HW4 + hw4;                    \
        Rx[buf] = x4[ibase];                                        \
        Gx[buf] = x4[ibase + HW4];                                  \
        Bx[buf] = x4[ibase + 2 * HW4];                              \
        obase_t[t] = ibase + c * HW4;                               \
    }

#define COMP_IDX(buf)                                               \
    {                                                               \
        const float RR[4] = {Rx[buf].x, Rx[buf].y, Rx[buf].z, Rx[buf].w}; \
        const float GG[4] = {Gx[buf].x, Gx[buf].y, Gx[buf].z, Gx[buf].w}; \
        const float BB[4] = {Bx[buf].x, Bx[buf].y, Bx[buf].z, Bx[buf].w}; \
        _Pragma("unroll")                                           \
        for (int k = 0; k < 4; ++k) {                               \
            const float sr = RR[k] * 32.0f;                         \
            const float sg = GG[k] * 32.0f;                         \
            const float sb = BB[k] * 32.0f;                         \
            const float fr = fminf(fmaxf(floorf(sr), 0.0f), 31.0f); \
            const float fg = fminf(fmaxf(floorf(sg), 0.0f), 31.0f); \
            const float fb = fminf(fmaxf(floorf(sb), 0.0f), 31.0f); \
            drA[buf][k] = sr - fr;                                  \
            dgA[buf][k] = sg - fg;                                  \
            dbA[buf][k] = sb - fb;                                  \
            idxA[buf][k] = ((int)fb * LUT_D + (int)fg) * LUT_D + (int)fr; \
        }                                                           \
    }

#define GATHER(buf)                                                 \
    {                                                               \
        _Pragma("unroll")                                           \
        for (int k = 0; k < 4; ++k) {                               \
            const int i0 = idxA[buf][k];                            \
            const int i1 = i0 + LUT_DD;                             \
            q[buf][k][0] = P[i0];                                   \
            q[buf][k][1] = P[i0 + LUT_D];   /* ds_read2 offset1:33 */ \
            q[buf][k][2] = P[i1];                                   \
            q[buf][k][3] = P[i1 + LUT_D];   /* ds_read2 offset1:33 */ \
        }                                                           \
    }

#define MATH_STORE(buf, t)                                          \
    {                                                               \
        float oo[4];                                                \
        _Pragma("unroll")                                           \
        for (int k = 0; k < 4; ++k) {                               \
            const float2 a = up2(q[buf][k][0]);                     \
            const float2 b = up2(q[buf][k][1]);                     \
            const float2 e = up2(q[buf][k][2]);                     \
            const float2 d = up2(q[buf][k][3]);                     \
            const float dr = drA[buf][k];                           \
            const float dg = dgA[buf][k];                           \
            const float db = dbA[buf][k];                           \
            const float l00 = a.x + dr * (a.y - a.x);               \
            const float l01 = b.x + dr * (b.y - b.x);               \
            const float l10 = e.x + dr * (e.y - e.x);               \
            const float l11 = d.x + dr * (d.y - d.x);               \
            const float l0  = l00 + dg * (l01 - l00);               \
            const float l1  = l10 + dg * (l11 - l10);               \
            oo[k] = l0 + db * (l1 - l0);                            \
        }                                                           \
        vfloat4 v = {oo[0], oo[1], oo[2], oo[3]};                   \
        __builtin_nontemporal_store(v, (vfloat4*)&o4[obase_t[t]]);  \
    }

    // Prologue: x(0), x(1) in flight before the staging barrier.
    LOAD_X(0, 0);
    LOAD_X(1, 1);
    __syncthreads();   // vmcnt(0) drain: staging AND x(0)/x(1) complete

    COMP_IDX(0);
    GATHER(0);

#pragma unroll
    for (int t = 0; t < ITERS; ++t) {
        const int cur = t & 1;
        const int nxt = cur ^ 1;
        if (t + 2 < ITERS) LOAD_X(t + 2, cur);  // x(t) already consumed at t-1
        if (t + 1 < ITERS) {
            COMP_IDX(nxt);
            GATHER(nxt);
        }
        MATH_STORE(cur, t);
    }
#undef LOAD_X
#undef COMP_IDX
#undef GATHER
#undef MATH_STORE
}

extern "C" void kernel_launch(void* const* d_in, const int* in_sizes, int n_in,
                              void* d_out, int out_size, void* d_ws, size_t ws_size,
                              hipStream_t stream) {
    const float*  lut = (const float*)d_in[0];   // [3, 33, 33, 33]
    const float*  x   = (const float*)d_in[1];   // [4, 3, 1024, 1024]
    float*        out = (float*)d_out;
    unsigned int* W   = (unsigned int*)d_ws;     // 3*CH_STRIDE u32 = 431,280 B

    const int pack_grid = (3 * LUT_N + 255) / 256;  // 422
    lut_pack_kernel<<<pack_grid, 256, 0, stream>>>(lut, W);

    const int grid = 3 * NCHUNKS;                    // 768
    const size_t lds_bytes = (size_t)STAGE_G * 16;   // 143,760 B
    lut3d_trilerp_kernel<<<grid, THREADS, lds_bytes, stream>>>(W, x, out);
}